// Round 5
// baseline (235.352 us; speedup 1.0000x reference)
//
#include <hip/hip_runtime.h>

#define CC 128
#define SB 16384   // T*H*W

typedef _Float16 half4_t __attribute__((ext_vector_type(4)));
typedef _Float16 half8_t __attribute__((ext_vector_type(8)));
typedef float    f32x4  __attribute__((ext_vector_type(4)));

// ---- workspace map ----
#define WH_OFF   0u         // 3*64*128 fp16 weights [set][m][k]  (dead after kC)
#define ABH_OFF  0u         // 8*64*64 fp16 ABt*1024 (k2 writes; WH dead by then)
#define BIAS_OFF 49152u     // 192 f32
#define CM_OFF   50176u     // 8*1024 f32 Cm
#define SUME_OFF 82944u     // 512 f32 (zeroed by k0, atomicAdd by kC)
#define PT_OFF   262144u    // 8*16384*64 fp16 P = e*V  [b][s][n]   (16MB)
#define VT_OFF   17039360u  // 8*16384*64 fp16 V        [b][s][n]   (16MB)
// AB per-block partials (1024*4096 f32 = 16.8MB) live in d_out's attn region
// (d_out+8388608): written by kC, read by k2, then fully overwritten by k4.

// ---------------------------------------------------------------- k0: setup
__global__ void k0_setup(const float* __restrict__ cond,
                         const float* __restrict__ W_phi, const float* __restrict__ b_phi,
                         const float* __restrict__ W_theta, const float* __restrict__ b_theta,
                         const float* __restrict__ W_rho, const float* __restrict__ b_rho,
                         const float* __restrict__ W1, const float* __restrict__ b1,
                         const float* __restrict__ W2, const float* __restrict__ b2,
                         char* __restrict__ wsc) {
  __shared__ float sc[64], sh1[64], red[256];
  int t = threadIdx.x, bid = blockIdx.x;
  if (bid < 8) {
    int b = bid;
    if (t < 64) sc[t] = cond[b*64 + t];
    __syncthreads();
    if (t < 64) {
      float acc = b1[t];
      for (int k = 0; k < 64; ++k) acc += sc[k] * W1[t*64 + k];
      sh1[t] = fmaxf(acc, 0.f);
    }
    __syncthreads();
    float ev[4]; float ps = 0.f;
    #pragma unroll
    for (int q = 0; q < 4; ++q) {
      int o = q*256 + t;
      float acc = b2[o];
      for (int k = 0; k < 64; ++k) acc += sh1[k] * W2[o*64 + k];
      ev[q] = __expf(fmaxf(acc, 0.f));
      ps += ev[q];
    }
    red[t] = ps; __syncthreads();
    for (int s = 128; s > 0; s >>= 1) { if (t < s) red[t] += red[t+s]; __syncthreads(); }
    float inv = 1.f / red[0];
    float* cm = (float*)(wsc + CM_OFF);
    #pragma unroll
    for (int q = 0; q < 4; ++q) cm[b*1024 + q*256 + t] = ev[q] * inv;
  } else {
    int r = bid - 8;
    _Float16* wh = (_Float16*)(wsc + WH_OFF);
    for (int i = r*256 + t; i < 24576; i += 2048) {
      int set = i >> 13, mk = i & 8191;
      const float* W = (set == 0) ? W_phi : (set == 1 ? W_theta : W_rho);
      wh[i] = (_Float16)W[mk];       // all W_* are [64][128] row-major already
    }
    if (r == 0 && t < 192) {
      float* bias = (float*)(wsc + BIAS_OFF);
      bias[t] = (t < 64) ? b_phi[t] : (t < 128 ? b_theta[t-64] : b_rho[t-128]);
    }
    if (r == 1) {
      float* se = (float*)(wsc + SUME_OFF);
      for (int i = t; i < 512; i += 256) se[i] = 0.f;
    }
  }
}

// ------------- kC: fused transpose + 3 convs (MFMA) + epilogues + AB partials
// grid 1024 = 8b * 128 chunks(128 s), 4 waves. Wave: 32 pos (2 n-tiles), all 64 outs.
// Frag maps (m89/m120-verified): A[m=ln][k=q*8+j], B[k=q*8+j][n=ln], D[m=q*4+r][n=ln].
// LDS 52736 B -> 3 blocks/CU (was 70656 -> 2): Xt_l dead after B-frag reg loads,
// so A_l/E_l alias it (round-4 lesson: occupancy 17% was the cap, not MFMA).
__global__ __launch_bounds__(256, 3) void kC_main(
    const float* __restrict__ x, const _Float16* __restrict__ wh,
    const float* __restrict__ bias, const float* __restrict__ cm,
    float* __restrict__ sumE, _Float16* __restrict__ vt,
    _Float16* __restrict__ pt, float* __restrict__ part) {
  __shared__ char smraw[52736];
  _Float16* Xt_l = (_Float16*)smraw;          // 128*136 halfs = 34816 B [s][c]
  float*    Xs   = (float*)(smraw + 34816);   // 128*33 f32 = 16896 B (transpose staging)
  _Float16* A_l  = (_Float16*)smraw;          // 64*136 halfs (aliases Xt_l)
  _Float16* E_l  = (_Float16*)(smraw + 17408);// 64*136 halfs (aliases Xt_l)
  float*    se_l = (float*)(smraw + 51712);   // 256 f32

  int t = threadIdx.x;
  int lane = t & 63, wv = t >> 6, ln = lane & 15, q = lane >> 4;
  int bid = blockIdx.x, b = bid >> 7, chunk = bid & 127;
  int s0 = chunk * 128;
  const float* xb = x + (size_t)b*CC*SB + s0;

  // ---- in-LDS transpose: x fp32 [c][s] -> Xt_l fp16 [s][c], 4 subtiles of 32 s ----
  #pragma unroll
  for (int st = 0; st < 4; ++st) {
    #pragma unroll
    for (int r = 0; r < 4; ++r) {
      int fid = r*256 + t;                    // 1024 float4 = 128c x 32s
      int c = fid >> 3, s4 = (fid & 7) << 2;
      *(float4*)&Xs[c*33 + s4] = *(const float4*)(xb + (size_t)c*SB + st*32 + s4);
    }
    __syncthreads();
    #pragma unroll
    for (int r = 0; r < 2; ++r) {
      int fid = r*256 + t;                    // 512 half8 = 32s x 16 c8-groups
      int s = fid >> 4, c8 = fid & 15;
      half8_t h;
      #pragma unroll
      for (int i = 0; i < 8; ++i) h[i] = (_Float16)Xs[(c8*8 + i)*33 + s];
      *(half8_t*)&Xt_l[(st*32 + s)*136 + c8*8] = h;
    }
    __syncthreads();                          // Xs reused next subtile
  }

  // B-fragments for this wave's 32 positions (kept in regs across all 3 sets)
  half8_t bf[2][4];
  int myp = wv * 32;
  #pragma unroll
  for (int nt = 0; nt < 2; ++nt)
    #pragma unroll
    for (int kk = 0; kk < 4; ++kk)
      bf[nt][kk] = *(half8_t*)&Xt_l[(myp + nt*16 + ln)*136 + kk*32 + q*8];
  __syncthreads();                            // Xt_l dead; A_l/E_l may now overwrite

  int gsl[2] = { s0 + myp + ln, s0 + myp + 16 + ln };
  float cmv[2] = { cm[b*1024 + (gsl[0] & 1023)], cm[b*1024 + (gsl[1] & 1023)] };

  half8_t af[4][4];
  f32x4 d[4][2];
  float ev[4][2][4];

  auto conv = [&](int setoff) {
    #pragma unroll
    for (int mt = 0; mt < 4; ++mt)
      #pragma unroll
      for (int kk = 0; kk < 4; ++kk)
        af[mt][kk] = *(const half8_t*)(wh + setoff + (mt*16 + ln)*128 + kk*32 + q*8);
    #pragma unroll
    for (int mt = 0; mt < 4; ++mt)
      #pragma unroll
      for (int nt = 0; nt < 2; ++nt)
        d[mt][nt] = (f32x4){0.f, 0.f, 0.f, 0.f};
    #pragma unroll
    for (int kk = 0; kk < 4; ++kk)
      #pragma unroll
      for (int mt = 0; mt < 4; ++mt)
        #pragma unroll
        for (int nt = 0; nt < 2; ++nt)
          d[mt][nt] = __builtin_amdgcn_mfma_f32_16x16x32_f16(af[mt][kk], bf[nt][kk],
                                                             d[mt][nt], 0, 0, 0);
  };

  // ---- set 0: phi -> A_l[m][s] fp16 ----
  conv(0);
  #pragma unroll
  for (int mt = 0; mt < 4; ++mt) {
    float bv[4]; *(float4*)bv = *(const float4*)(bias + mt*16 + q*4);
    #pragma unroll
    for (int nt = 0; nt < 2; ++nt)
      #pragma unroll
      for (int r = 0; r < 4; ++r)
        A_l[(mt*16 + q*4 + r)*136 + myp + nt*16 + ln] = (_Float16)(d[mt][nt][r] + bv[r]);
  }

  // ---- set 1: theta -> e (regs), ec -> E_l, sumE partials ----
  conv(8192);
  float sp[4][4];
  #pragma unroll
  for (int mt = 0; mt < 4; ++mt) {
    float bv[4]; *(float4*)bv = *(const float4*)(bias + 64 + mt*16 + q*4);
    #pragma unroll
    for (int r = 0; r < 4; ++r) {
      #pragma unroll
      for (int nt = 0; nt < 2; ++nt) {
        float e = __expf(d[mt][nt][r] + bv[r]);
        ev[mt][nt][r] = e;
        E_l[(mt*16 + q*4 + r)*136 + myp + nt*16 + ln] = (_Float16)(e * cmv[nt]);
      }
      sp[mt][r] = ev[mt][0][r] + ev[mt][1][r];
    }
  }
  #pragma unroll
  for (int mt = 0; mt < 4; ++mt)
    #pragma unroll
    for (int r = 0; r < 4; ++r) {
      float v = sp[mt][r];
      v += __shfl_xor(v, 1); v += __shfl_xor(v, 2);
      v += __shfl_xor(v, 4); v += __shfl_xor(v, 8);
      sp[mt][r] = v;
    }
  if (ln == 0) {
    #pragma unroll
    for (int mt = 0; mt < 4; ++mt)
      #pragma unroll
      for (int r = 0; r < 4; ++r)
        se_l[wv*64 + mt*16 + q*4 + r] = sp[mt][r];
  }

  // ---- set 2: rho -> V (channel softmax), write V_t and P_t = e*V ----
  conv(16384);
  #pragma unroll
  for (int mt = 0; mt < 4; ++mt) {
    float bv[4]; *(float4*)bv = *(const float4*)(bias + 128 + mt*16 + q*4);
    #pragma unroll
    for (int nt = 0; nt < 2; ++nt)
      #pragma unroll
      for (int r = 0; r < 4; ++r)
        d[mt][nt][r] = __expf(d[mt][nt][r] + bv[r]);
  }
  float cs[2] = {0.f, 0.f};
  #pragma unroll
  for (int mt = 0; mt < 4; ++mt)
    #pragma unroll
    for (int nt = 0; nt < 2; ++nt)
      #pragma unroll
      for (int r = 0; r < 4; ++r) cs[nt] += d[mt][nt][r];
  #pragma unroll
  for (int nt = 0; nt < 2; ++nt) {            // sum over 4 quads -> all 64 channels
    cs[nt] += __shfl_xor(cs[nt], 16);
    cs[nt] += __shfl_xor(cs[nt], 32);
    cs[nt] = 1.f / cs[nt];
  }
  #pragma unroll
  for (int nt = 0; nt < 2; ++nt) {
    size_t grow = (size_t)b*SB + gsl[nt];
    _Float16* vrow = vt + grow*64;
    _Float16* prow = pt + grow*64;
    #pragma unroll
    for (int mt = 0; mt < 4; ++mt) {
      half4_t hv, hp;
      #pragma unroll
      for (int r = 0; r < 4; ++r) {
        float vv = d[mt][nt][r] * cs[nt];
        hv[r] = (_Float16)vv;
        hp[r] = (_Float16)(vv * ev[mt][nt][r]);
      }
      *(half4_t*)(vrow + mt*16 + q*4) = hv;
      *(half4_t*)(prow + mt*16 + q*4) = hp;
    }
  }
  __syncthreads();                             // A_l, E_l, se_l complete

  if (t < 64) {
    float ssum = se_l[t] + se_l[64+t] + se_l[128+t] + se_l[192+t];
    atomicAdd(&sumE[b*64 + t], ssum);
  }

  // ---- AB rank-128 update via MFMA: AB[m][n] += A[m][s] * ec[n][s] ----
  f32x4 dab[4];
  #pragma unroll
  for (int n2 = 0; n2 < 4; ++n2) dab[n2] = (f32x4){0.f, 0.f, 0.f, 0.f};
  #pragma unroll
  for (int kk = 0; kk < 4; ++kk) {
    half8_t aab = *(half8_t*)&A_l[(wv*16 + ln)*136 + kk*32 + q*8];
    #pragma unroll
    for (int n2 = 0; n2 < 4; ++n2) {
      half8_t bab = *(half8_t*)&E_l[(n2*16 + ln)*136 + kk*32 + q*8];
      dab[n2] = __builtin_amdgcn_mfma_f32_16x16x32_f16(aab, bab, dab[n2], 0, 0, 0);
    }
  }
  float* pp = part + (size_t)bid*4096;
  #pragma unroll
  for (int n2 = 0; n2 < 4; ++n2)
    #pragma unroll
    for (int r = 0; r < 4; ++r)
      pp[(wv*16 + q*4 + r)*64 + n2*16 + ln] = dab[n2][r];
}

// ---------------- k2: reduce AB partials, scale 1024/sumE, fp16 [b][m][n]
__global__ void k2_reduce(const float* __restrict__ part, const float* __restrict__ sumE,
                          _Float16* __restrict__ abh) {
  int idx = blockIdx.x*256 + threadIdx.x;      // 32768
  int b = idx >> 12, mn = idx & 4095, n = mn & 63;
  const float* p = part + (size_t)b*128*4096 + mn;
  float s = 0.f;
  #pragma unroll 4
  for (int k = 0; k < 128; ++k) s += p[(size_t)k*4096];
  // x1024: keeps fp16 values well clear of denormals (AB ~ 2e-4); k3 undoes it
  abh[idx] = (_Float16)(s * (1024.f / sumE[b*64 + n]));
}

// ---------------------------------------------------------------- k3: Z GEMM (MFMA)
// grid 512 = 8b * 64 chunks(256 s). Z[m][s] = sum_n ABt[m][n] * V[n][s].
__global__ __launch_bounds__(256) void k3_z(const _Float16* __restrict__ abh,
                                            const _Float16* __restrict__ vt,
                                            float* __restrict__ zout) {
  __shared__ _Float16 Ah[64*72];
  int t = threadIdx.x;
  int lane = t & 63, wv = t >> 6, ln = lane & 15, q = lane >> 4;
  int bid = blockIdx.x, b = bid >> 6, chunk = bid & 63;
  int s0 = chunk * 256;
  #pragma unroll
  for (int r = 0; r < 2; ++r) {
    int fid = r*256 + t;
    int m = fid >> 3, n8 = fid & 7;
    *(half8_t*)&Ah[m*72 + n8*8] = *(const half8_t*)(abh + b*4096 + m*64 + n8*8);
  }
  __syncthreads();
  half8_t a8[4][2];
  #pragma unroll
  for (int mt = 0; mt < 4; ++mt)
    #pragma unroll
    for (int kk = 0; kk < 2; ++kk)
      a8[mt][kk] = *(half8_t*)&Ah[(mt*16 + ln)*72 + kk*32 + q*8];
  int sw = s0 + wv*64;
  #pragma unroll
  for (int nt = 0; nt < 4; ++nt) {
    int sb = sw + nt*16 + ln;
    const _Float16* vrow = vt + ((size_t)b*SB + sb)*64;
    half8_t b8[2];
    b8[0] = *(const half8_t*)(vrow + q*8);
    b8[1] = *(const half8_t*)(vrow + 32 + q*8);
    f32x4 dz[4];
    #pragma unroll
    for (int mt = 0; mt < 4; ++mt) dz[mt] = (f32x4){0.f, 0.f, 0.f, 0.f};
    #pragma unroll
    for (int kk = 0; kk < 2; ++kk)
      #pragma unroll
      for (int mt = 0; mt < 4; ++mt)
        dz[mt] = __builtin_amdgcn_mfma_f32_16x16x32_f16(a8[mt][kk], b8[kk], dz[mt], 0, 0, 0);
    #pragma unroll
    for (int mt = 0; mt < 4; ++mt)
      #pragma unroll
      for (int r = 0; r < 4; ++r)
        zout[((size_t)(b*64 + mt*16 + q*4 + r))*SB + sb] = dz[mt][r] * (1.f/1024.f);
  }
}

// ------------------------------- k4: attn[n][hw][t] = P[s][n] / sumE[n], t-innermost
// grid 512 = 8b * 64 hw-blocks(16 hw). LDS transpose: rows=s(16t x 16hw), cols=n.
__global__ __launch_bounds__(256) void k4_attn(const _Float16* __restrict__ pt,
                                               const float* __restrict__ sumE,
                                               float* __restrict__ outA) {
  __shared__ _Float16 P_l[256*72];
  int t = threadIdx.x, bid = blockIdx.x;
  int b = bid >> 6, hw0 = (bid & 63) * 16;
  int st = t >> 4, h = t & 15;
  int s = st*1024 + hw0 + h;
  const _Float16* prow = pt + ((size_t)b*SB + s)*64;
  #pragma unroll
  for (int c8 = 0; c8 < 8; ++c8)
    *(half8_t*)&P_l[t*72 + c8*8] = *(const half8_t*)(prow + c8*8);
  __syncthreads();
  int n = t >> 2, oc = t & 3;
  float ri = 1.f / sumE[b*64 + n];
  float* orow = outA + 8388608 + (size_t)(b*64 + n)*SB + hw0*16;
  #pragma unroll
  for (int i = 0; i < 16; ++i) {
    int j = oc*64 + i*4;
    int hh = j >> 4, stb = j & 15;
    float w[4];
    #pragma unroll
    for (int r = 0; r < 4; ++r)
      w[r] = (float)P_l[((stb + r)*16 + hh)*72 + n] * ri;
    *(float4*)(orow + j) = *(float4*)w;
  }
}

extern "C" void kernel_launch(void* const* d_in, const int* in_sizes, int n_in,
                              void* d_out, int out_size, void* d_ws, size_t ws_size,
                              hipStream_t stream) {
  const float* input   = (const float*)d_in[0];
  const float* cond    = (const float*)d_in[1];
  const float* W_phi   = (const float*)d_in[2];
  const float* b_phi   = (const float*)d_in[3];
  const float* W_theta = (const float*)d_in[4];
  const float* b_theta = (const float*)d_in[5];
  const float* W_rho   = (const float*)d_in[6];
  const float* b_rho   = (const float*)d_in[7];
  const float* W1      = (const float*)d_in[8];
  const float* b1      = (const float*)d_in[9];
  const float* W2      = (const float*)d_in[10];
  const float* b2      = (const float*)d_in[11];
  char* wsc = (char*)d_ws;
  float* out = (float*)d_out;

  const _Float16* wh = (const _Float16*)(wsc + WH_OFF);
  _Float16* abh  = (_Float16*)(wsc + ABH_OFF);
  const float* bias = (const float*)(wsc + BIAS_OFF);
  const float* cmp  = (const float*)(wsc + CM_OFF);
  float* sumE  = (float*)(wsc + SUME_OFF);
  _Float16* pt = (_Float16*)(wsc + PT_OFF);
  _Float16* vt = (_Float16*)(wsc + VT_OFF);
  float* part  = out + 8388608;        // scratch in attn region (k4 overwrites later)

  hipLaunchKernelGGL(k0_setup, dim3(16), dim3(256), 0, stream,
                     cond, W_phi, b_phi, W_theta, b_theta, W_rho, b_rho,
                     W1, b1, W2, b2, wsc);
  hipLaunchKernelGGL(kC_main, dim3(1024), dim3(256), 0, stream,
                     input, wh, bias, cmp, sumE, vt, pt, part);
  hipLaunchKernelGGL(k2_reduce, dim3(128), dim3(256), 0, stream, part, sumE, abh);
  hipLaunchKernelGGL(k3_z, dim3(512), dim3(256), 0, stream, abh, vt, out);
  hipLaunchKernelGGL(k4_attn, dim3(512), dim3(256), 0, stream, pt, sumE, out);
}